// Round 1
// baseline (462.900 us; speedup 1.0000x reference)
//
#include <hip/hip_runtime.h>
#include <math.h>

#define IN_CH 128
#define H1N 8
#define C1N 16
#define C2N 64
#define NEG_SLOPE 0.2f

// ---------------- CSR build ----------------

__global__ void k_hist(const int* __restrict__ dst, int E, int N, int* __restrict__ deg) {
    int stride = gridDim.x * blockDim.x;
    int Etot = E + N;
    for (int i = blockIdx.x * blockDim.x + threadIdx.x; i < Etot; i += stride) {
        int d = (i < E) ? dst[i] : (i - E);
        atomicAdd(&deg[d], 1);
    }
}

__global__ void k_scan(const int* __restrict__ deg, int N,
                       int* __restrict__ offsets, int* __restrict__ cursor) {
    // single block, 1024 threads
    __shared__ int part[1024];
    int t = threadIdx.x;
    int chunk = (N + 1023) >> 10;
    int lo = t * chunk;
    int hi = lo + chunk; if (hi > N) hi = N;
    int s = 0;
    for (int i = lo; i < hi; ++i) s += deg[i];
    part[t] = s;
    __syncthreads();
    for (int off = 1; off < 1024; off <<= 1) {
        int v = (t >= off) ? part[t - off] : 0;
        __syncthreads();
        part[t] += v;
        __syncthreads();
    }
    int run = (t == 0) ? 0 : part[t - 1];
    for (int i = lo; i < hi; ++i) {
        offsets[i] = run;
        cursor[i]  = run;
        run += deg[i];
    }
    if (lo < N && hi == N) offsets[N] = run;
}

__global__ void k_scatter(const int* __restrict__ src, const int* __restrict__ dst,
                          int E, int N, int* __restrict__ cursor, int* __restrict__ csr) {
    int stride = gridDim.x * blockDim.x;
    int Etot = E + N;
    for (int i = blockIdx.x * blockDim.x + threadIdx.x; i < Etot; i += stride) {
        int s, d;
        if (i < E) { s = src[i]; d = dst[i]; }
        else       { s = d = i - E; }
        int pos = atomicAdd(&cursor[d], 1);
        csr[pos] = s;
    }
}

// ---------------- GEMM: C[N,KOUT] = A[N,128] @ W[128,KOUT] ----------------

template <int KOUT>
__global__ __launch_bounds__(256) void k_gemm(const float* __restrict__ A,
                                              const float* __restrict__ W,
                                              int N, float* __restrict__ C) {
    constexpr int CG  = KOUT / 4;   // column groups of 4 (float4)
    constexpr int TY  = 256 / CG;   // row-group count
    constexpr int RPT = 64 / TY;    // rows per thread
    __shared__ float As[64][16];
    __shared__ float Ws[16][KOUT];
    int t = threadIdx.x;
    int row0 = blockIdx.x * 64;
    int tx = t % CG, ty = t / CG;

    float4 acc[RPT];
#pragma unroll
    for (int i = 0; i < RPT; ++i) acc[i] = make_float4(0.f, 0.f, 0.f, 0.f);

    for (int k0 = 0; k0 < IN_CH; k0 += 16) {
        // stage A: 64x16
        {
            int r  = t >> 2;
            int cc = (t & 3) * 4;
            int gr = row0 + r;
            float4 v = make_float4(0.f, 0.f, 0.f, 0.f);
            if (gr < N) v = *(const float4*)(A + (size_t)gr * IN_CH + k0 + cc);
            *(float4*)(&As[r][cc]) = v;
        }
        // stage W: 16xKOUT
        {
            constexpr int TOT = 16 * KOUT / 4;
            for (int idx = t; idx < TOT; idx += 256) {
                int rr = idx / (KOUT / 4);
                int cc = (idx % (KOUT / 4)) * 4;
                *(float4*)(&Ws[rr][cc]) = *(const float4*)(W + (size_t)(k0 + rr) * KOUT + cc);
            }
        }
        __syncthreads();
#pragma unroll
        for (int kk = 0; kk < 16; ++kk) {
            float4 w = *(const float4*)(&Ws[kk][tx * 4]);
#pragma unroll
            for (int i = 0; i < RPT; ++i) {
                float a = As[ty * RPT + i][kk];
                acc[i].x += a * w.x; acc[i].y += a * w.y;
                acc[i].z += a * w.z; acc[i].w += a * w.w;
            }
        }
        __syncthreads();
    }
#pragma unroll
    for (int i = 0; i < RPT; ++i) {
        int gr = row0 + ty * RPT + i;
        if (gr < N) *(float4*)(C + (size_t)gr * KOUT + tx * 4) = acc[i];
    }
}

// ---------------- attention coefficients ----------------

__global__ void k_att1(const float* __restrict__ h1,
                       const float* __restrict__ att_s, const float* __restrict__ att_d,
                       int N, float* __restrict__ as1, float* __restrict__ ad1) {
    int stride = gridDim.x * blockDim.x;
    int tot = N * H1N;
    for (int i = blockIdx.x * blockDim.x + threadIdx.x; i < tot; i += stride) {
        int v = i >> 3, h = i & 7;
        const float4* hp = (const float4*)(h1 + (size_t)v * IN_CH + h * C1N);
        const float4* sp = (const float4*)(att_s + h * C1N);
        const float4* dp = (const float4*)(att_d + h * C1N);
        float s = 0.f, d = 0.f;
#pragma unroll
        for (int j = 0; j < 4; ++j) {
            float4 hv = hp[j], sv = sp[j], dv = dp[j];
            s += hv.x * sv.x + hv.y * sv.y + hv.z * sv.z + hv.w * sv.w;
            d += hv.x * dv.x + hv.y * dv.y + hv.z * dv.z + hv.w * dv.w;
        }
        as1[i] = s;
        ad1[i] = d;
    }
}

__global__ void k_att2(const float* __restrict__ h2,
                       const float* __restrict__ att_s, const float* __restrict__ att_d,
                       int N, float* __restrict__ as2, float* __restrict__ ad2) {
    int wid  = (blockIdx.x * blockDim.x + threadIdx.x) >> 6;
    int lane = threadIdx.x & 63;
    if (wid >= N) return;
    float hv = h2[(size_t)wid * C2N + lane];
    float s = hv * att_s[lane];
    float d = hv * att_d[lane];
#pragma unroll
    for (int o = 32; o >= 1; o >>= 1) {
        s += __shfl_xor(s, o);
        d += __shfl_xor(d, o);
    }
    if (lane == 0) { as2[wid] = s; ad2[wid] = d; }
}

// ---------------- layer 1 aggregation (+bias +ELU) ----------------
// wave per node; lane owns channels 2*lane, 2*lane+1; head = lane/8

__global__ void k_agg1(const float* __restrict__ h1,
                       const float* __restrict__ as1, const float* __restrict__ ad1,
                       const int* __restrict__ offsets, const int* __restrict__ csr,
                       const float* __restrict__ b1,
                       int N, float* __restrict__ h2in) {
    int wid  = (blockIdx.x * blockDim.x + threadIdx.x) >> 6;
    int lane = threadIdx.x & 63;
    if (wid >= N) return;
    int v = wid;
    int hidx = lane >> 3;
    float ad = ad1[v * H1N + hidx];
    float m = -INFINITY, denom = 0.f, acc0 = 0.f, acc1 = 0.f;
    int beg = offsets[v], end = offsets[v + 1];
    for (int j = beg; j < end; ++j) {
        int s = csr[j];
        float asv = as1[s * H1N + hidx];
        float lg = asv + ad;
        lg = (lg > 0.f) ? lg : NEG_SLOPE * lg;
        float mn = fmaxf(m, lg);
        float r = __expf(m - mn);
        float p = __expf(lg - mn);
        float2 hv = *(const float2*)(h1 + (size_t)s * IN_CH + lane * 2);
        denom = denom * r + p;
        acc0  = acc0 * r + p * hv.x;
        acc1  = acc1 * r + p * hv.y;
        m = mn;
    }
    float inv = 1.f / (denom + 1e-16f);
    float o0 = acc0 * inv + b1[lane * 2];
    float o1 = acc1 * inv + b1[lane * 2 + 1];
    o0 = (o0 > 0.f) ? o0 : expm1f(o0);   // ELU
    o1 = (o1 > 0.f) ? o1 : expm1f(o1);
    float2 ov; ov.x = o0; ov.y = o1;
    *(float2*)(h2in + (size_t)v * IN_CH + lane * 2) = ov;
}

// ---------------- layer 2 aggregation (+bias) + log_softmax ----------------
// wave per node; lane owns channel lane (64 channels, single head)

__global__ void k_agg2(const float* __restrict__ h2,
                       const float* __restrict__ as2, const float* __restrict__ ad2,
                       const int* __restrict__ offsets, const int* __restrict__ csr,
                       const float* __restrict__ b2,
                       int N, float* __restrict__ out) {
    int wid  = (blockIdx.x * blockDim.x + threadIdx.x) >> 6;
    int lane = threadIdx.x & 63;
    if (wid >= N) return;
    int v = wid;
    float ad = ad2[v];
    float m = -INFINITY, denom = 0.f, acc = 0.f;
    int beg = offsets[v], end = offsets[v + 1];
    for (int j = beg; j < end; ++j) {
        int s = csr[j];
        float lg = as2[s] + ad;
        lg = (lg > 0.f) ? lg : NEG_SLOPE * lg;
        float mn = fmaxf(m, lg);
        float r = __expf(m - mn);
        float p = __expf(lg - mn);
        float hv = h2[(size_t)s * C2N + lane];
        denom = denom * r + p;
        acc   = acc * r + p * hv;
        m = mn;
    }
    float o = acc / (denom + 1e-16f) + b2[lane];
    // log_softmax over 64 lanes
    float mx = o;
#pragma unroll
    for (int off = 32; off >= 1; off >>= 1) mx = fmaxf(mx, __shfl_xor(mx, off));
    float e = __expf(o - mx);
    float se = e;
#pragma unroll
    for (int off = 32; off >= 1; off >>= 1) se += __shfl_xor(se, off);
    out[(size_t)v * C2N + lane] = o - mx - logf(se);
}

// ---------------- launch ----------------

extern "C" void kernel_launch(void* const* d_in, const int* in_sizes, int n_in,
                              void* d_out, int out_size, void* d_ws, size_t ws_size,
                              hipStream_t stream) {
    const float* x      = (const float*)d_in[0];
    const int*   ei     = (const int*)d_in[1];
    const float* W1     = (const float*)d_in[2];
    const float* att_s1 = (const float*)d_in[3];
    const float* att_d1 = (const float*)d_in[4];
    const float* b1     = (const float*)d_in[5];
    const float* W2     = (const float*)d_in[6];
    const float* att_s2 = (const float*)d_in[7];
    const float* att_d2 = (const float*)d_in[8];
    const float* b2     = (const float*)d_in[9];

    int N = in_sizes[0] / IN_CH;
    int E = in_sizes[1] / 2;
    const int* srcA = ei;
    const int* dstA = ei + E;
    int Etot = E + N;

    // workspace carve (256B aligned)
    char* p = (char*)d_ws;
    auto carve = [&](size_t bytes) {
        void* r = (void*)p;
        p += (bytes + 255) & ~(size_t)255;
        return r;
    };
    float* h1   = (float*)carve((size_t)N * IN_CH * 4);
    float* h2in = (float*)carve((size_t)N * IN_CH * 4);
    float* as1  = (float*)carve((size_t)N * H1N * 4);
    float* ad1  = (float*)carve((size_t)N * H1N * 4);
    float* as2  = (float*)carve((size_t)N * 4);
    float* ad2  = (float*)carve((size_t)N * 4);
    int* deg     = (int*)carve((size_t)N * 4);
    int* offsets = (int*)carve((size_t)(N + 1) * 4);
    int* cursor  = (int*)carve((size_t)N * 4);
    int* csr     = (int*)carve((size_t)Etot * 4);
    float* h2 = h1;  // h1 dead after agg1; reuse for layer-2 features

    // CSR build
    hipMemsetAsync(deg, 0, (size_t)N * 4, stream);
    k_hist<<<2048, 256, 0, stream>>>(dstA, E, N, deg);
    k_scan<<<1, 1024, 0, stream>>>(deg, N, offsets, cursor);
    k_scatter<<<2048, 256, 0, stream>>>(srcA, dstA, E, N, cursor, csr);

    // layer 1
    k_gemm<128><<<(N + 63) / 64, 256, 0, stream>>>(x, W1, N, h1);
    k_att1<<<1024, 256, 0, stream>>>(h1, att_s1, att_d1, N, as1, ad1);
    k_agg1<<<(N * 64 + 255) / 256, 256, 0, stream>>>(h1, as1, ad1, offsets, csr, b1, N, h2in);

    // layer 2
    k_gemm<64><<<(N + 63) / 64, 256, 0, stream>>>(h2in, W2, N, h2);
    k_att2<<<(N * 64 + 255) / 256, 256, 0, stream>>>(h2, att_s2, att_d2, N, as2, ad2);
    k_agg2<<<(N * 64 + 255) / 256, 256, 0, stream>>>(h2, as2, ad2, offsets, csr, b2, N, (float*)d_out);
}

// Round 2
// 362.271 us; speedup vs baseline: 1.2778x; 1.2778x over previous
//
#include <hip/hip_runtime.h>
#include <math.h>

#define IN_CH 128
#define H1N 8
#define C1N 16
#define C2N 64
#define NEG_SLOPE 0.2f
#define SCAN_CHUNK 2048

// ---------------- CSR build ----------------

__global__ void k_hist(const int* __restrict__ dst, int E, int N, int* __restrict__ deg) {
    int stride = gridDim.x * blockDim.x;
    int Etot = E + N;
    for (int i = blockIdx.x * blockDim.x + threadIdx.x; i < Etot; i += stride) {
        int d = (i < E) ? dst[i] : (i - E);
        atomicAdd(&deg[d], 1);
    }
}

// stage 1: per-block sums of deg over SCAN_CHUNK-sized chunks
__global__ void k_blocksum(const int* __restrict__ deg, int N, int* __restrict__ blkSum) {
    __shared__ int red[256];
    int b = blockIdx.x;
    int base = b * SCAN_CHUNK;
    int t = threadIdx.x;
    int s = 0;
    for (int i = t; i < SCAN_CHUNK; i += 256) {
        int g = base + i;
        if (g < N) s += deg[g];
    }
    red[t] = s;
    __syncthreads();
    for (int off = 128; off >= 1; off >>= 1) {
        if (t < off) red[t] += red[t + off];
        __syncthreads();
    }
    if (t == 0) blkSum[b] = red[0];
}

// stage 2: single small block scans the G block sums (G <= 256) -> exclusive bases
__global__ void k_scanblk(int* __restrict__ blkSum, int G, int* __restrict__ blkBase,
                          int N, int* __restrict__ offsets) {
    __shared__ int sh[256];
    int t = threadIdx.x;
    sh[t] = (t < G) ? blkSum[t] : 0;
    __syncthreads();
    for (int off = 1; off < 256; off <<= 1) {
        int v = (t >= off) ? sh[t - off] : 0;
        __syncthreads();
        sh[t] += v;
        __syncthreads();
    }
    if (t < G) blkBase[t] = (t == 0) ? 0 : sh[t - 1];
    if (t == 255) offsets[N] = sh[255];   // total
}

// stage 3: per-block exclusive scan of deg, offset by blkBase
__global__ void k_finalize(const int* __restrict__ deg, int N,
                           const int* __restrict__ blkBase,
                           int* __restrict__ offsets, int* __restrict__ cursor) {
    __shared__ int sh[256];
    int b = blockIdx.x;
    int base = b * SCAN_CHUNK;
    int t = threadIdx.x;
    int lo = base + t * 8;
    int d[8];
    int s = 0;
#pragma unroll
    for (int j = 0; j < 8; ++j) {
        int g = lo + j;
        d[j] = (g < N) ? deg[g] : 0;
        s += d[j];
    }
    sh[t] = s;
    __syncthreads();
    for (int off = 1; off < 256; off <<= 1) {
        int v = (t >= off) ? sh[t - off] : 0;
        __syncthreads();
        sh[t] += v;
        __syncthreads();
    }
    int run = blkBase[b] + ((t == 0) ? 0 : sh[t - 1]);
#pragma unroll
    for (int j = 0; j < 8; ++j) {
        int g = lo + j;
        if (g < N) { offsets[g] = run; cursor[g] = run; }
        run += d[j];
    }
}

__global__ void k_scatter(const int* __restrict__ src, const int* __restrict__ dst,
                          int E, int N, int* __restrict__ cursor, int* __restrict__ csr) {
    int stride = gridDim.x * blockDim.x;
    int Etot = E + N;
    for (int i = blockIdx.x * blockDim.x + threadIdx.x; i < Etot; i += stride) {
        int s, d;
        if (i < E) { s = src[i]; d = dst[i]; }
        else       { s = d = i - E; }
        int pos = atomicAdd(&cursor[d], 1);
        csr[pos] = s;
    }
}

// ---------------- GEMM: C[N,KOUT] = A[N,128] @ W[128,KOUT] ----------------

template <int KOUT>
__global__ __launch_bounds__(256) void k_gemm(const float* __restrict__ A,
                                              const float* __restrict__ W,
                                              int N, float* __restrict__ C) {
    constexpr int CG  = KOUT / 4;   // column groups of 4 (float4)
    constexpr int TY  = 256 / CG;   // row-group count
    constexpr int RPT = 64 / TY;    // rows per thread
    __shared__ float As[64][16];
    __shared__ float Ws[16][KOUT];
    int t = threadIdx.x;
    int row0 = blockIdx.x * 64;
    int tx = t % CG, ty = t / CG;

    float4 acc[RPT];
#pragma unroll
    for (int i = 0; i < RPT; ++i) acc[i] = make_float4(0.f, 0.f, 0.f, 0.f);

    for (int k0 = 0; k0 < IN_CH; k0 += 16) {
        {
            int r  = t >> 2;
            int cc = (t & 3) * 4;
            int gr = row0 + r;
            float4 v = make_float4(0.f, 0.f, 0.f, 0.f);
            if (gr < N) v = *(const float4*)(A + (size_t)gr * IN_CH + k0 + cc);
            *(float4*)(&As[r][cc]) = v;
        }
        {
            constexpr int TOT = 16 * KOUT / 4;
            for (int idx = t; idx < TOT; idx += 256) {
                int rr = idx / (KOUT / 4);
                int cc = (idx % (KOUT / 4)) * 4;
                *(float4*)(&Ws[rr][cc]) = *(const float4*)(W + (size_t)(k0 + rr) * KOUT + cc);
            }
        }
        __syncthreads();
#pragma unroll
        for (int kk = 0; kk < 16; ++kk) {
            float4 w = *(const float4*)(&Ws[kk][tx * 4]);
#pragma unroll
            for (int i = 0; i < RPT; ++i) {
                float a = As[ty * RPT + i][kk];
                acc[i].x += a * w.x; acc[i].y += a * w.y;
                acc[i].z += a * w.z; acc[i].w += a * w.w;
            }
        }
        __syncthreads();
    }
#pragma unroll
    for (int i = 0; i < RPT; ++i) {
        int gr = row0 + ty * RPT + i;
        if (gr < N) *(float4*)(C + (size_t)gr * KOUT + tx * 4) = acc[i];
    }
}

// ---------------- attention coefficients ----------------

__global__ void k_att1(const float* __restrict__ h1,
                       const float* __restrict__ att_s, const float* __restrict__ att_d,
                       int N, float* __restrict__ as1, float* __restrict__ ad1) {
    int stride = gridDim.x * blockDim.x;
    int tot = N * H1N;
    for (int i = blockIdx.x * blockDim.x + threadIdx.x; i < tot; i += stride) {
        int v = i >> 3, h = i & 7;
        const float4* hp = (const float4*)(h1 + (size_t)v * IN_CH + h * C1N);
        const float4* sp = (const float4*)(att_s + h * C1N);
        const float4* dp = (const float4*)(att_d + h * C1N);
        float s = 0.f, d = 0.f;
#pragma unroll
        for (int j = 0; j < 4; ++j) {
            float4 hv = hp[j], sv = sp[j], dv = dp[j];
            s += hv.x * sv.x + hv.y * sv.y + hv.z * sv.z + hv.w * sv.w;
            d += hv.x * dv.x + hv.y * dv.y + hv.z * dv.z + hv.w * dv.w;
        }
        as1[i] = s;
        ad1[i] = d;
    }
}

__global__ void k_att2(const float* __restrict__ h2,
                       const float* __restrict__ att_s, const float* __restrict__ att_d,
                       int N, float* __restrict__ as2, float* __restrict__ ad2) {
    int wid  = (blockIdx.x * blockDim.x + threadIdx.x) >> 6;
    int lane = threadIdx.x & 63;
    if (wid >= N) return;
    float hv = h2[(size_t)wid * C2N + lane];
    float s = hv * att_s[lane];
    float d = hv * att_d[lane];
#pragma unroll
    for (int o = 32; o >= 1; o >>= 1) {
        s += __shfl_xor(s, o);
        d += __shfl_xor(d, o);
    }
    if (lane == 0) { as2[wid] = s; ad2[wid] = d; }
}

// ---------------- layer 1 aggregation (+bias +ELU) ----------------

__global__ void k_agg1(const float* __restrict__ h1,
                       const float* __restrict__ as1, const float* __restrict__ ad1,
                       const int* __restrict__ offsets, const int* __restrict__ csr,
                       const float* __restrict__ b1,
                       int N, float* __restrict__ h2in) {
    int wid  = (blockIdx.x * blockDim.x + threadIdx.x) >> 6;
    int lane = threadIdx.x & 63;
    if (wid >= N) return;
    int v = wid;
    int hidx = lane >> 3;
    float ad = ad1[v * H1N + hidx];
    float m = -INFINITY, denom = 0.f, acc0 = 0.f, acc1 = 0.f;
    int beg = offsets[v], end = offsets[v + 1];
    for (int j = beg; j < end; ++j) {
        int s = csr[j];
        float asv = as1[s * H1N + hidx];
        float lg = asv + ad;
        lg = (lg > 0.f) ? lg : NEG_SLOPE * lg;
        float mn = fmaxf(m, lg);
        float r = __expf(m - mn);
        float p = __expf(lg - mn);
        float2 hv = *(const float2*)(h1 + (size_t)s * IN_CH + lane * 2);
        denom = denom * r + p;
        acc0  = acc0 * r + p * hv.x;
        acc1  = acc1 * r + p * hv.y;
        m = mn;
    }
    float inv = 1.f / (denom + 1e-16f);
    float o0 = acc0 * inv + b1[lane * 2];
    float o1 = acc1 * inv + b1[lane * 2 + 1];
    o0 = (o0 > 0.f) ? o0 : expm1f(o0);
    o1 = (o1 > 0.f) ? o1 : expm1f(o1);
    float2 ov; ov.x = o0; ov.y = o1;
    *(float2*)(h2in + (size_t)v * IN_CH + lane * 2) = ov;
}

// ---------------- layer 2 aggregation (+bias) + log_softmax ----------------

__global__ void k_agg2(const float* __restrict__ h2,
                       const float* __restrict__ as2, const float* __restrict__ ad2,
                       const int* __restrict__ offsets, const int* __restrict__ csr,
                       const float* __restrict__ b2,
                       int N, float* __restrict__ out) {
    int wid  = (blockIdx.x * blockDim.x + threadIdx.x) >> 6;
    int lane = threadIdx.x & 63;
    if (wid >= N) return;
    int v = wid;
    float ad = ad2[v];
    float m = -INFINITY, denom = 0.f, acc = 0.f;
    int beg = offsets[v], end = offsets[v + 1];
    for (int j = beg; j < end; ++j) {
        int s = csr[j];
        float lg = as2[s] + ad;
        lg = (lg > 0.f) ? lg : NEG_SLOPE * lg;
        float mn = fmaxf(m, lg);
        float r = __expf(m - mn);
        float p = __expf(lg - mn);
        float hv = h2[(size_t)s * C2N + lane];
        denom = denom * r + p;
        acc   = acc * r + p * hv;
        m = mn;
    }
    float o = acc / (denom + 1e-16f) + b2[lane];
    float mx = o;
#pragma unroll
    for (int off = 32; off >= 1; off >>= 1) mx = fmaxf(mx, __shfl_xor(mx, off));
    float e = __expf(o - mx);
    float se = e;
#pragma unroll
    for (int off = 32; off >= 1; off >>= 1) se += __shfl_xor(se, off);
    out[(size_t)v * C2N + lane] = o - mx - logf(se);
}

// ---------------- launch ----------------

extern "C" void kernel_launch(void* const* d_in, const int* in_sizes, int n_in,
                              void* d_out, int out_size, void* d_ws, size_t ws_size,
                              hipStream_t stream) {
    const float* x      = (const float*)d_in[0];
    const int*   ei     = (const int*)d_in[1];
    const float* W1     = (const float*)d_in[2];
    const float* att_s1 = (const float*)d_in[3];
    const float* att_d1 = (const float*)d_in[4];
    const float* b1     = (const float*)d_in[5];
    const float* W2     = (const float*)d_in[6];
    const float* att_s2 = (const float*)d_in[7];
    const float* att_d2 = (const float*)d_in[8];
    const float* b2     = (const float*)d_in[9];

    int N = in_sizes[0] / IN_CH;
    int E = in_sizes[1] / 2;
    const int* srcA = ei;
    const int* dstA = ei + E;
    int Etot = E + N;
    int G = (N + SCAN_CHUNK - 1) / SCAN_CHUNK;   // scan blocks (25 for N=50000)

    char* p = (char*)d_ws;
    auto carve = [&](size_t bytes) {
        void* r = (void*)p;
        p += (bytes + 255) & ~(size_t)255;
        return r;
    };
    float* h1   = (float*)carve((size_t)N * IN_CH * 4);
    float* h2in = (float*)carve((size_t)N * IN_CH * 4);
    float* as1  = (float*)carve((size_t)N * H1N * 4);
    float* ad1  = (float*)carve((size_t)N * H1N * 4);
    float* as2  = (float*)carve((size_t)N * 4);
    float* ad2  = (float*)carve((size_t)N * 4);
    int* deg     = (int*)carve((size_t)N * 4);
    int* offsets = (int*)carve((size_t)(N + 1) * 4);
    int* cursor  = (int*)carve((size_t)N * 4);
    int* csr     = (int*)carve((size_t)Etot * 4);
    int* blkSum  = (int*)carve(256 * 4);
    int* blkBase = (int*)carve(256 * 4);
    float* h2 = h1;  // h1 dead after agg1; reuse

    // CSR build
    hipMemsetAsync(deg, 0, (size_t)N * 4, stream);
    k_hist<<<2048, 256, 0, stream>>>(dstA, E, N, deg);
    k_blocksum<<<G, 256, 0, stream>>>(deg, N, blkSum);
    k_scanblk<<<1, 256, 0, stream>>>(blkSum, G, blkBase, N, offsets);
    k_finalize<<<G, 256, 0, stream>>>(deg, N, blkBase, offsets, cursor);
    k_scatter<<<2048, 256, 0, stream>>>(srcA, dstA, E, N, cursor, csr);

    // layer 1
    k_gemm<128><<<(N + 63) / 64, 256, 0, stream>>>(x, W1, N, h1);
    k_att1<<<1024, 256, 0, stream>>>(h1, att_s1, att_d1, N, as1, ad1);
    k_agg1<<<(N * 64 + 255) / 256, 256, 0, stream>>>(h1, as1, ad1, offsets, csr, b1, N, h2in);

    // layer 2
    k_gemm<64><<<(N + 63) / 64, 256, 0, stream>>>(h2in, W2, N, h2);
    k_att2<<<(N * 64 + 255) / 256, 256, 0, stream>>>(h2, att_s2, att_d2, N, as2, ad2);
    k_agg2<<<(N * 64 + 255) / 256, 256, 0, stream>>>(h2, as2, ad2, offsets, csr, b2, N, (float*)d_out);
}

// Round 3
// 341.255 us; speedup vs baseline: 1.3565x; 1.0616x over previous
//
#include <hip/hip_runtime.h>
#include <math.h>

#define IN_CH 128
#define H1N 8
#define C1N 16
#define C2N 64
#define NEG_SLOPE 0.2f
#define SCAN_CHUNK 2048

typedef unsigned short ushortT;

__device__ __forceinline__ ushortT f2bf(float f) {
    unsigned u = __float_as_uint(f);
    unsigned r = u + 0x7FFFu + ((u >> 16) & 1u);   // round-to-nearest-even
    return (ushortT)(r >> 16);
}
__device__ __forceinline__ float bf2f(ushortT b) {
    return __uint_as_float(((unsigned)b) << 16);
}

// ---------------- CSR build ----------------

__global__ void k_hist(const int* __restrict__ dst, int E, int N, int* __restrict__ deg) {
    int stride = gridDim.x * blockDim.x;
    int Etot = E + N;
    for (int i = blockIdx.x * blockDim.x + threadIdx.x; i < Etot; i += stride) {
        int d = (i < E) ? dst[i] : (i - E);
        atomicAdd(&deg[d], 1);
    }
}

__global__ void k_blocksum(const int* __restrict__ deg, int N, int* __restrict__ blkSum) {
    __shared__ int red[256];
    int b = blockIdx.x;
    int base = b * SCAN_CHUNK;
    int t = threadIdx.x;
    int s = 0;
    for (int i = t; i < SCAN_CHUNK; i += 256) {
        int g = base + i;
        if (g < N) s += deg[g];
    }
    red[t] = s;
    __syncthreads();
    for (int off = 128; off >= 1; off >>= 1) {
        if (t < off) red[t] += red[t + off];
        __syncthreads();
    }
    if (t == 0) blkSum[b] = red[0];
}

__global__ void k_scanblk(int* __restrict__ blkSum, int G, int* __restrict__ blkBase,
                          int N, int* __restrict__ offsets) {
    __shared__ int sh[256];
    int t = threadIdx.x;
    sh[t] = (t < G) ? blkSum[t] : 0;
    __syncthreads();
    for (int off = 1; off < 256; off <<= 1) {
        int v = (t >= off) ? sh[t - off] : 0;
        __syncthreads();
        sh[t] += v;
        __syncthreads();
    }
    if (t < G) blkBase[t] = (t == 0) ? 0 : sh[t - 1];
    if (t == 255) offsets[N] = sh[255];
}

__global__ void k_finalize(const int* __restrict__ deg, int N,
                           const int* __restrict__ blkBase,
                           int* __restrict__ offsets, int* __restrict__ cursor) {
    __shared__ int sh[256];
    int b = blockIdx.x;
    int base = b * SCAN_CHUNK;
    int t = threadIdx.x;
    int lo = base + t * 8;
    int d[8];
    int s = 0;
#pragma unroll
    for (int j = 0; j < 8; ++j) {
        int g = lo + j;
        d[j] = (g < N) ? deg[g] : 0;
        s += d[j];
    }
    sh[t] = s;
    __syncthreads();
    for (int off = 1; off < 256; off <<= 1) {
        int v = (t >= off) ? sh[t - off] : 0;
        __syncthreads();
        sh[t] += v;
        __syncthreads();
    }
    int run = blkBase[b] + ((t == 0) ? 0 : sh[t - 1]);
#pragma unroll
    for (int j = 0; j < 8; ++j) {
        int g = lo + j;
        if (g < N) { offsets[g] = run; cursor[g] = run; }
        run += d[j];
    }
}

__global__ void k_scatter(const int* __restrict__ src, const int* __restrict__ dst,
                          int E, int N, int* __restrict__ cursor, int* __restrict__ csr) {
    int stride = gridDim.x * blockDim.x;
    int Etot = E + N;
    for (int i = blockIdx.x * blockDim.x + threadIdx.x; i < Etot; i += stride) {
        int s, d;
        if (i < E) { s = src[i]; d = dst[i]; }
        else       { s = d = i - E; }
        int pos = atomicAdd(&cursor[d], 1);
        csr[pos] = s;
    }
}

// ---------------- GEMM + fused attention coefficients ----------------
// C_bf[N,KOUT] (bf16) = A[N,128] @ W[128,KOUT]; also as[v,h] = <row_h, att_s>,
// ad[v,h] = <row_h, att_d>, computed from the f32 accumulators.

template <int KOUT, int HEADS>
__global__ __launch_bounds__(256) void k_gemm_att(const float* __restrict__ A,
                                                  const float* __restrict__ W,
                                                  const float* __restrict__ att_s,
                                                  const float* __restrict__ att_d,
                                                  int N, ushortT* __restrict__ Cbf,
                                                  float* __restrict__ as_,
                                                  float* __restrict__ ad_) {
    constexpr int CG  = KOUT / 4;          // float4 column groups
    constexpr int TY  = 256 / CG;          // row groups
    constexpr int RPT = 64 / TY;           // rows per thread
    constexpr int RW  = (KOUT / HEADS) / 4; // col-groups per head (reduce width)
    static_assert(RW == 4 || RW == 16, "reduce width");
    __shared__ float As[64][16];
    __shared__ float Ws[16][KOUT];
    int t = threadIdx.x;
    int row0 = blockIdx.x * 64;
    int tx = t % CG, ty = t / CG;

    float4 acc[RPT];
#pragma unroll
    for (int i = 0; i < RPT; ++i) acc[i] = make_float4(0.f, 0.f, 0.f, 0.f);

    for (int k0 = 0; k0 < IN_CH; k0 += 16) {
        {
            int r  = t >> 2;
            int cc = (t & 3) * 4;
            int gr = row0 + r;
            float4 v = make_float4(0.f, 0.f, 0.f, 0.f);
            if (gr < N) v = *(const float4*)(A + (size_t)gr * IN_CH + k0 + cc);
            *(float4*)(&As[r][cc]) = v;
        }
        {
            constexpr int TOT = 16 * KOUT / 4;
            for (int idx = t; idx < TOT; idx += 256) {
                int rr = idx / (KOUT / 4);
                int cc = (idx % (KOUT / 4)) * 4;
                *(float4*)(&Ws[rr][cc]) = *(const float4*)(W + (size_t)(k0 + rr) * KOUT + cc);
            }
        }
        __syncthreads();
#pragma unroll
        for (int kk = 0; kk < 16; ++kk) {
            float4 w = *(const float4*)(&Ws[kk][tx * 4]);
#pragma unroll
            for (int i = 0; i < RPT; ++i) {
                float a = As[ty * RPT + i][kk];
                acc[i].x += a * w.x; acc[i].y += a * w.y;
                acc[i].z += a * w.z; acc[i].w += a * w.w;
            }
        }
        __syncthreads();
    }

    // epilogue: att partials + bf16 store
    float4 s4 = *(const float4*)(att_s + tx * 4);
    float4 d4 = *(const float4*)(att_d + tx * 4);
#pragma unroll
    for (int i = 0; i < RPT; ++i) {
        int gr = row0 + ty * RPT + i;
        float as = acc[i].x * s4.x + acc[i].y * s4.y + acc[i].z * s4.z + acc[i].w * s4.w;
        float ad = acc[i].x * d4.x + acc[i].y * d4.y + acc[i].z * d4.z + acc[i].w * d4.w;
#pragma unroll
        for (int o = 1; o < RW; o <<= 1) {
            as += __shfl_xor(as, o);
            ad += __shfl_xor(ad, o);
        }
        if (gr < N) {
            ushort4 pk;
            pk.x = f2bf(acc[i].x); pk.y = f2bf(acc[i].y);
            pk.z = f2bf(acc[i].z); pk.w = f2bf(acc[i].w);
            *(ushort4*)(Cbf + (size_t)gr * KOUT + tx * 4) = pk;
            if ((tx % RW) == 0) {
                int h = tx / RW;
                as_[(size_t)gr * HEADS + h] = as;
                ad_[(size_t)gr * HEADS + h] = ad;
            }
        }
    }
}

// ---------------- layer 1 aggregation (+bias +ELU) ----------------
// wave per node; lane owns channels 2*lane, 2*lane+1; head = lane/8

__global__ void k_agg1(const ushortT* __restrict__ h1bf,
                       const float* __restrict__ as1, const float* __restrict__ ad1,
                       const int* __restrict__ offsets, const int* __restrict__ csr,
                       const float* __restrict__ b1,
                       int N, float* __restrict__ h2in) {
    int wid  = (blockIdx.x * blockDim.x + threadIdx.x) >> 6;
    int lane = threadIdx.x & 63;
    if (wid >= N) return;
    int v = wid;
    int hidx = lane >> 3;
    float ad = ad1[v * H1N + hidx];
    float m = -INFINITY, denom = 0.f, acc0 = 0.f, acc1 = 0.f;
    int beg = offsets[v], end = offsets[v + 1];
    for (int j = beg; j < end; ++j) {
        int s = csr[j];
        float asv = as1[s * H1N + hidx];
        float lg = asv + ad;
        lg = (lg > 0.f) ? lg : NEG_SLOPE * lg;
        float mn = fmaxf(m, lg);
        float r = __expf(m - mn);
        float p = __expf(lg - mn);
        unsigned hv = *(const unsigned*)(h1bf + (size_t)s * IN_CH + lane * 2);
        float x0 = bf2f((ushortT)(hv & 0xFFFFu));
        float x1 = bf2f((ushortT)(hv >> 16));
        denom = denom * r + p;
        acc0  = acc0 * r + p * x0;
        acc1  = acc1 * r + p * x1;
        m = mn;
    }
    float inv = 1.f / (denom + 1e-16f);
    float o0 = acc0 * inv + b1[lane * 2];
    float o1 = acc1 * inv + b1[lane * 2 + 1];
    o0 = (o0 > 0.f) ? o0 : expm1f(o0);
    o1 = (o1 > 0.f) ? o1 : expm1f(o1);
    float2 ov; ov.x = o0; ov.y = o1;
    *(float2*)(h2in + (size_t)v * IN_CH + lane * 2) = ov;
}

// ---------------- layer 2 aggregation (+bias) + log_softmax ----------------
// wave per node; lane owns channel lane

__global__ void k_agg2(const ushortT* __restrict__ h2bf,
                       const float* __restrict__ as2, const float* __restrict__ ad2,
                       const int* __restrict__ offsets, const int* __restrict__ csr,
                       const float* __restrict__ b2,
                       int N, float* __restrict__ out) {
    int wid  = (blockIdx.x * blockDim.x + threadIdx.x) >> 6;
    int lane = threadIdx.x & 63;
    if (wid >= N) return;
    int v = wid;
    float ad = ad2[v];
    float m = -INFINITY, denom = 0.f, acc = 0.f;
    int beg = offsets[v], end = offsets[v + 1];
    for (int j = beg; j < end; ++j) {
        int s = csr[j];
        float lg = as2[s] + ad;
        lg = (lg > 0.f) ? lg : NEG_SLOPE * lg;
        float mn = fmaxf(m, lg);
        float r = __expf(m - mn);
        float p = __expf(lg - mn);
        float hv = bf2f(h2bf[(size_t)s * C2N + lane]);
        denom = denom * r + p;
        acc   = acc * r + p * hv;
        m = mn;
    }
    float o = acc / (denom + 1e-16f) + b2[lane];
    float mx = o;
#pragma unroll
    for (int off = 32; off >= 1; off >>= 1) mx = fmaxf(mx, __shfl_xor(mx, off));
    float e = __expf(o - mx);
    float se = e;
#pragma unroll
    for (int off = 32; off >= 1; off >>= 1) se += __shfl_xor(se, off);
    out[(size_t)v * C2N + lane] = o - mx - logf(se);
}

// ---------------- launch ----------------

extern "C" void kernel_launch(void* const* d_in, const int* in_sizes, int n_in,
                              void* d_out, int out_size, void* d_ws, size_t ws_size,
                              hipStream_t stream) {
    const float* x      = (const float*)d_in[0];
    const int*   ei     = (const int*)d_in[1];
    const float* W1     = (const float*)d_in[2];
    const float* att_s1 = (const float*)d_in[3];
    const float* att_d1 = (const float*)d_in[4];
    const float* b1     = (const float*)d_in[5];
    const float* W2     = (const float*)d_in[6];
    const float* att_s2 = (const float*)d_in[7];
    const float* att_d2 = (const float*)d_in[8];
    const float* b2     = (const float*)d_in[9];

    int N = in_sizes[0] / IN_CH;
    int E = in_sizes[1] / 2;
    const int* srcA = ei;
    const int* dstA = ei + E;
    int Etot = E + N;
    int G = (N + SCAN_CHUNK - 1) / SCAN_CHUNK;

    char* p = (char*)d_ws;
    auto carve = [&](size_t bytes) {
        void* r = (void*)p;
        p += (bytes + 255) & ~(size_t)255;
        return r;
    };
    ushortT* h1bf = (ushortT*)carve((size_t)N * IN_CH * 2);
    ushortT* h2bf = (ushortT*)carve((size_t)N * C2N * 2);
    float* h2in = (float*)carve((size_t)N * IN_CH * 4);
    float* as1  = (float*)carve((size_t)N * H1N * 4);
    float* ad1  = (float*)carve((size_t)N * H1N * 4);
    float* as2  = (float*)carve((size_t)N * 4);
    float* ad2  = (float*)carve((size_t)N * 4);
    int* deg     = (int*)carve((size_t)N * 4);
    int* offsets = (int*)carve((size_t)(N + 1) * 4);
    int* cursor  = (int*)carve((size_t)N * 4);
    int* csr     = (int*)carve((size_t)Etot * 4);
    int* blkSum  = (int*)carve(256 * 4);
    int* blkBase = (int*)carve(256 * 4);

    // CSR build
    hipMemsetAsync(deg, 0, (size_t)N * 4, stream);
    k_hist<<<2048, 256, 0, stream>>>(dstA, E, N, deg);
    k_blocksum<<<G, 256, 0, stream>>>(deg, N, blkSum);
    k_scanblk<<<1, 256, 0, stream>>>(blkSum, G, blkBase, N, offsets);
    k_finalize<<<G, 256, 0, stream>>>(deg, N, blkBase, offsets, cursor);
    k_scatter<<<2048, 256, 0, stream>>>(srcA, dstA, E, N, cursor, csr);

    // layer 1
    k_gemm_att<128, 8><<<(N + 63) / 64, 256, 0, stream>>>(x, W1, att_s1, att_d1,
                                                          N, h1bf, as1, ad1);
    k_agg1<<<(N * 64 + 255) / 256, 256, 0, stream>>>(h1bf, as1, ad1, offsets, csr, b1, N, h2in);

    // layer 2
    k_gemm_att<64, 1><<<(N + 63) / 64, 256, 0, stream>>>(h2in, W2, att_s2, att_d2,
                                                         N, h2bf, as2, ad2);
    k_agg2<<<(N * 64 + 255) / 256, 256, 0, stream>>>(h2bf, as2, ad2, offsets, csr, b2, N, (float*)d_out);
}

// Round 4
// 253.354 us; speedup vs baseline: 1.8271x; 1.3469x over previous
//
#include <hip/hip_runtime.h>
#include <math.h>

#define IN_CH 128
#define H1N 8
#define C1N 16
#define C2N 64
#define NEG_SLOPE 0.2f
#define SCAN_CHUNK 2048

typedef unsigned short ushortT;

__device__ __forceinline__ ushortT f2bf(float f) {
    unsigned u = __float_as_uint(f);
    unsigned r = u + 0x7FFFu + ((u >> 16) & 1u);
    return (ushortT)(r >> 16);
}
__device__ __forceinline__ float bf2f(ushortT b) {
    return __uint_as_float(((unsigned)b) << 16);
}
__device__ __forceinline__ float leaky(float x) {
    return (x > 0.f) ? x : NEG_SLOPE * x;
}

// ---------------- CSR build ----------------

__global__ void k_hist(const int* __restrict__ dst, int E, int N, int* __restrict__ deg) {
    int stride = gridDim.x * blockDim.x;
    int Etot = E + N;
    for (int i = blockIdx.x * blockDim.x + threadIdx.x; i < Etot; i += stride) {
        int d = (i < E) ? dst[i] : (i - E);
        atomicAdd(&deg[d], 1);
    }
}

__global__ void k_blocksum(const int* __restrict__ deg, int N, int* __restrict__ blkSum) {
    __shared__ int red[256];
    int b = blockIdx.x;
    int base = b * SCAN_CHUNK;
    int t = threadIdx.x;
    int s = 0;
    for (int i = t; i < SCAN_CHUNK; i += 256) {
        int g = base + i;
        if (g < N) s += deg[g];
    }
    red[t] = s;
    __syncthreads();
    for (int off = 128; off >= 1; off >>= 1) {
        if (t < off) red[t] += red[t + off];
        __syncthreads();
    }
    if (t == 0) blkSum[b] = red[0];
}

__global__ void k_scanblk(int* __restrict__ blkSum, int G, int* __restrict__ blkBase,
                          int N, int* __restrict__ offsets) {
    __shared__ int sh[256];
    int t = threadIdx.x;
    sh[t] = (t < G) ? blkSum[t] : 0;
    __syncthreads();
    for (int off = 1; off < 256; off <<= 1) {
        int v = (t >= off) ? sh[t - off] : 0;
        __syncthreads();
        sh[t] += v;
        __syncthreads();
    }
    if (t < G) blkBase[t] = (t == 0) ? 0 : sh[t - 1];
    if (t == 255) offsets[N] = sh[255];
}

__global__ void k_finalize(const int* __restrict__ deg, int N,
                           const int* __restrict__ blkBase,
                           int* __restrict__ offsets, int* __restrict__ cursor) {
    __shared__ int sh[256];
    int b = blockIdx.x;
    int base = b * SCAN_CHUNK;
    int t = threadIdx.x;
    int lo = base + t * 8;
    int d[8];
    int s = 0;
#pragma unroll
    for (int j = 0; j < 8; ++j) {
        int g = lo + j;
        d[j] = (g < N) ? deg[g] : 0;
        s += d[j];
    }
    sh[t] = s;
    __syncthreads();
    for (int off = 1; off < 256; off <<= 1) {
        int v = (t >= off) ? sh[t - off] : 0;
        __syncthreads();
        sh[t] += v;
        __syncthreads();
    }
    int run = blkBase[b] + ((t == 0) ? 0 : sh[t - 1]);
#pragma unroll
    for (int j = 0; j < 8; ++j) {
        int g = lo + j;
        if (g < N) { offsets[g] = run; cursor[g] = run; }
        run += d[j];
    }
}

__global__ void k_scatter(const int* __restrict__ src, const int* __restrict__ dst,
                          int E, int N, int* __restrict__ cursor, int* __restrict__ csr) {
    int stride = gridDim.x * blockDim.x;
    int Etot = E + N;
    for (int i = blockIdx.x * blockDim.x + threadIdx.x; i < Etot; i += stride) {
        int s, d;
        if (i < E) { s = src[i]; d = dst[i]; }
        else       { s = d = i - E; }
        int pos = atomicAdd(&cursor[d], 1);
        csr[pos] = s;
    }
}

// ---------------- GEMM + fused attention coefficients ----------------

template <int KOUT, int HEADS>
__global__ __launch_bounds__(256) void k_gemm_att(const float* __restrict__ A,
                                                  const float* __restrict__ W,
                                                  const float* __restrict__ att_s,
                                                  const float* __restrict__ att_d,
                                                  int N, ushortT* __restrict__ Cbf,
                                                  float* __restrict__ as_,
                                                  float* __restrict__ ad_) {
    constexpr int CG  = KOUT / 4;
    constexpr int TY  = 256 / CG;
    constexpr int RPT = 64 / TY;
    constexpr int RW  = (KOUT / HEADS) / 4;
    static_assert(RW == 4 || RW == 16, "reduce width");
    __shared__ float As[64][16];
    __shared__ float Ws[16][KOUT];
    int t = threadIdx.x;
    int row0 = blockIdx.x * 64;
    int tx = t % CG, ty = t / CG;

    float4 acc[RPT];
#pragma unroll
    for (int i = 0; i < RPT; ++i) acc[i] = make_float4(0.f, 0.f, 0.f, 0.f);

    for (int k0 = 0; k0 < IN_CH; k0 += 16) {
        {
            int r  = t >> 2;
            int cc = (t & 3) * 4;
            int gr = row0 + r;
            float4 v = make_float4(0.f, 0.f, 0.f, 0.f);
            if (gr < N) v = *(const float4*)(A + (size_t)gr * IN_CH + k0 + cc);
            *(float4*)(&As[r][cc]) = v;
        }
        {
            constexpr int TOT = 16 * KOUT / 4;
            for (int idx = t; idx < TOT; idx += 256) {
                int rr = idx / (KOUT / 4);
                int cc = (idx % (KOUT / 4)) * 4;
                *(float4*)(&Ws[rr][cc]) = *(const float4*)(W + (size_t)(k0 + rr) * KOUT + cc);
            }
        }
        __syncthreads();
#pragma unroll
        for (int kk = 0; kk < 16; ++kk) {
            float4 w = *(const float4*)(&Ws[kk][tx * 4]);
#pragma unroll
            for (int i = 0; i < RPT; ++i) {
                float a = As[ty * RPT + i][kk];
                acc[i].x += a * w.x; acc[i].y += a * w.y;
                acc[i].z += a * w.z; acc[i].w += a * w.w;
            }
        }
        __syncthreads();
    }

    float4 s4 = *(const float4*)(att_s + tx * 4);
    float4 d4 = *(const float4*)(att_d + tx * 4);
#pragma unroll
    for (int i = 0; i < RPT; ++i) {
        int gr = row0 + ty * RPT + i;
        float as = acc[i].x * s4.x + acc[i].y * s4.y + acc[i].z * s4.z + acc[i].w * s4.w;
        float ad = acc[i].x * d4.x + acc[i].y * d4.y + acc[i].z * d4.z + acc[i].w * d4.w;
#pragma unroll
        for (int o = 1; o < RW; o <<= 1) {
            as += __shfl_xor(as, o);
            ad += __shfl_xor(ad, o);
        }
        if (gr < N) {
            ushort4 pk;
            pk.x = f2bf(acc[i].x); pk.y = f2bf(acc[i].y);
            pk.z = f2bf(acc[i].z); pk.w = f2bf(acc[i].w);
            *(ushort4*)(Cbf + (size_t)gr * KOUT + tx * 4) = pk;
            if ((tx % RW) == 0) {
                int h = tx / RW;
                as_[(size_t)gr * HEADS + h] = as;
                ad_[(size_t)gr * HEADS + h] = ad;
            }
        }
    }
}

// ---------------- layer 1 aggregation (+bias +ELU) ----------------
// wave per node; lane owns channels 2*lane, 2*lane+1; head = lane/8.
// No max-subtraction (logits bounded, exp-safe); unroll x4 for MLP.

__global__ void k_agg1(const ushortT* __restrict__ h1bf,
                       const float* __restrict__ as1, const float* __restrict__ ad1,
                       const int* __restrict__ offsets, const int* __restrict__ csr,
                       const float* __restrict__ b1,
                       int N, float* __restrict__ h2in) {
    int wid  = (blockIdx.x * blockDim.x + threadIdx.x) >> 6;
    int lane = threadIdx.x & 63;
    if (wid >= N) return;
    int v = wid;
    int hidx = lane >> 3;
    float ad = ad1[v * H1N + hidx];
    float denom = 0.f, acc0 = 0.f, acc1 = 0.f;
    int beg = offsets[v], end = offsets[v + 1];
    int j = beg;
    for (; j + 4 <= end; j += 4) {
        int s0 = csr[j], s1 = csr[j + 1], s2 = csr[j + 2], s3 = csr[j + 3];
        float a0 = as1[s0 * H1N + hidx];
        float a1 = as1[s1 * H1N + hidx];
        float a2 = as1[s2 * H1N + hidx];
        float a3 = as1[s3 * H1N + hidx];
        unsigned q0 = *(const unsigned*)(h1bf + (size_t)s0 * IN_CH + lane * 2);
        unsigned q1 = *(const unsigned*)(h1bf + (size_t)s1 * IN_CH + lane * 2);
        unsigned q2 = *(const unsigned*)(h1bf + (size_t)s2 * IN_CH + lane * 2);
        unsigned q3 = *(const unsigned*)(h1bf + (size_t)s3 * IN_CH + lane * 2);
        float p0 = __expf(leaky(a0 + ad));
        float p1 = __expf(leaky(a1 + ad));
        float p2 = __expf(leaky(a2 + ad));
        float p3 = __expf(leaky(a3 + ad));
        denom += (p0 + p1) + (p2 + p3);
        acc0 = fmaf(p0, bf2f((ushortT)(q0 & 0xFFFFu)), acc0);
        acc1 = fmaf(p0, bf2f((ushortT)(q0 >> 16)), acc1);
        acc0 = fmaf(p1, bf2f((ushortT)(q1 & 0xFFFFu)), acc0);
        acc1 = fmaf(p1, bf2f((ushortT)(q1 >> 16)), acc1);
        acc0 = fmaf(p2, bf2f((ushortT)(q2 & 0xFFFFu)), acc0);
        acc1 = fmaf(p2, bf2f((ushortT)(q2 >> 16)), acc1);
        acc0 = fmaf(p3, bf2f((ushortT)(q3 & 0xFFFFu)), acc0);
        acc1 = fmaf(p3, bf2f((ushortT)(q3 >> 16)), acc1);
    }
    for (; j < end; ++j) {
        int s = csr[j];
        float a = as1[s * H1N + hidx];
        unsigned q = *(const unsigned*)(h1bf + (size_t)s * IN_CH + lane * 2);
        float p = __expf(leaky(a + ad));
        denom += p;
        acc0 = fmaf(p, bf2f((ushortT)(q & 0xFFFFu)), acc0);
        acc1 = fmaf(p, bf2f((ushortT)(q >> 16)), acc1);
    }
    float inv = 1.f / (denom + 1e-16f);
    float o0 = acc0 * inv + b1[lane * 2];
    float o1 = acc1 * inv + b1[lane * 2 + 1];
    o0 = (o0 > 0.f) ? o0 : expm1f(o0);
    o1 = (o1 > 0.f) ? o1 : expm1f(o1);
    float2 ov; ov.x = o0; ov.y = o1;
    *(float2*)(h2in + (size_t)v * IN_CH + lane * 2) = ov;
}

// ---------------- layer 2 aggregation (+bias) + log_softmax ----------------

__global__ void k_agg2(const ushortT* __restrict__ h2bf,
                       const float* __restrict__ as2, const float* __restrict__ ad2,
                       const int* __restrict__ offsets, const int* __restrict__ csr,
                       const float* __restrict__ b2,
                       int N, float* __restrict__ out) {
    int wid  = (blockIdx.x * blockDim.x + threadIdx.x) >> 6;
    int lane = threadIdx.x & 63;
    if (wid >= N) return;
    int v = wid;
    float ad = ad2[v];
    float denom = 0.f, acc = 0.f;
    int beg = offsets[v], end = offsets[v + 1];
    int j = beg;
    for (; j + 4 <= end; j += 4) {
        int s0 = csr[j], s1 = csr[j + 1], s2 = csr[j + 2], s3 = csr[j + 3];
        float a0 = as2[s0], a1 = as2[s1], a2 = as2[s2], a3 = as2[s3];
        float x0 = bf2f(h2bf[(size_t)s0 * C2N + lane]);
        float x1 = bf2f(h2bf[(size_t)s1 * C2N + lane]);
        float x2 = bf2f(h2bf[(size_t)s2 * C2N + lane]);
        float x3 = bf2f(h2bf[(size_t)s3 * C2N + lane]);
        float p0 = __expf(leaky(a0 + ad));
        float p1 = __expf(leaky(a1 + ad));
        float p2 = __expf(leaky(a2 + ad));
        float p3 = __expf(leaky(a3 + ad));
        denom += (p0 + p1) + (p2 + p3);
        acc = fmaf(p0, x0, acc);
        acc = fmaf(p1, x1, acc);
        acc = fmaf(p2, x2, acc);
        acc = fmaf(p3, x3, acc);
    }
    for (; j < end; ++j) {
        int s = csr[j];
        float p = __expf(leaky(as2[s] + ad));
        float x = bf2f(h2bf[(size_t)s * C2N + lane]);
        denom += p;
        acc = fmaf(p, x, acc);
    }
    float o = acc / (denom + 1e-16f) + b2[lane];
    float mx = o;
#pragma unroll
    for (int off = 32; off >= 1; off >>= 1) mx = fmaxf(mx, __shfl_xor(mx, off));
    float e = __expf(o - mx);
    float se = e;
#pragma unroll
    for (int off = 32; off >= 1; off >>= 1) se += __shfl_xor(se, off);
    out[(size_t)v * C2N + lane] = o - mx - logf(se);
}

// ---------------- launch ----------------

extern "C" void kernel_launch(void* const* d_in, const int* in_sizes, int n_in,
                              void* d_out, int out_size, void* d_ws, size_t ws_size,
                              hipStream_t stream) {
    const float* x      = (const float*)d_in[0];
    const int*   ei     = (const int*)d_in[1];
    const float* W1     = (const float*)d_in[2];
    const float* att_s1 = (const float*)d_in[3];
    const float* att_d1 = (const float*)d_in[4];
    const float* b1     = (const float*)d_in[5];
    const float* W2     = (const float*)d_in[6];
    const float* att_s2 = (const float*)d_in[7];
    const float* att_d2 = (const float*)d_in[8];
    const float* b2     = (const float*)d_in[9];

    int N = in_sizes[0] / IN_CH;
    int E = in_sizes[1] / 2;
    const int* srcA = ei;
    const int* dstA = ei + E;
    int Etot = E + N;
    int G = (N + SCAN_CHUNK - 1) / SCAN_CHUNK;

    char* p = (char*)d_ws;
    auto carve = [&](size_t bytes) {
        void* r = (void*)p;
        p += (bytes + 255) & ~(size_t)255;
        return r;
    };
    ushortT* h1bf = (ushortT*)carve((size_t)N * IN_CH * 2);
    ushortT* h2bf = (ushortT*)carve((size_t)N * C2N * 2);
    float* h2in = (float*)carve((size_t)N * IN_CH * 4);
    float* as1  = (float*)carve((size_t)N * H1N * 4);
    float* ad1  = (float*)carve((size_t)N * H1N * 4);
    float* as2  = (float*)carve((size_t)N * 4);
    float* ad2  = (float*)carve((size_t)N * 4);
    int* deg     = (int*)carve((size_t)N * 4);
    int* offsets = (int*)carve((size_t)(N + 1) * 4);
    int* cursor  = (int*)carve((size_t)N * 4);
    int* csr     = (int*)carve((size_t)Etot * 4);
    int* blkSum  = (int*)carve(256 * 4);
    int* blkBase = (int*)carve(256 * 4);

    hipMemsetAsync(deg, 0, (size_t)N * 4, stream);
    k_hist<<<2048, 256, 0, stream>>>(dstA, E, N, deg);
    k_blocksum<<<G, 256, 0, stream>>>(deg, N, blkSum);
    k_scanblk<<<1, 256, 0, stream>>>(blkSum, G, blkBase, N, offsets);
    k_finalize<<<G, 256, 0, stream>>>(deg, N, blkBase, offsets, cursor);
    k_scatter<<<2048, 256, 0, stream>>>(srcA, dstA, E, N, cursor, csr);

    k_gemm_att<128, 8><<<(N + 63) / 64, 256, 0, stream>>>(x, W1, att_s1, att_d1,
                                                          N, h1bf, as1, ad1);
    k_agg1<<<(N * 64 + 255) / 256, 256, 0, stream>>>(h1bf, as1, ad1, offsets, csr, b1, N, h2in);

    k_gemm_att<64, 1><<<(N + 63) / 64, 256, 0, stream>>>(h2in, W2, att_s2, att_d2,
                                                         N, h2bf, as2, ad2);
    k_agg2<<<(N * 64 + 255) / 256, 256, 0, stream>>>(h2bf, as2, ad2, offsets, csr, b2, N, (float*)d_out);
}